// Round 1
// baseline (2543.753 us; speedup 1.0000x reference)
//
#include <hip/hip_runtime.h>

// LIF scan: B=16 batches, S=256, H=128, N=64 neurons.
// T = S*H = 32768 sequential steps per (b, n) chain; 1024 independent chains.
// Outputs: outs[B][S][N][H] then spikes[B][S][N][H], fp32, concatenated in d_out.
// Bit-exactness with the numpy fp32 sequential reference is required: spike
// decisions are hard thresholds on sequentially-rounded sums, so no
// reassociation of the accumulation is allowed.

namespace {
constexpr int kB = 16;
constexpr int kS = 256;
constexpr int kH = 128;
constexpr int kN = 64;
constexpr int kT = kS * kH;          // 32768 steps per chain
constexpr int kPerB = kS * kN * kH;  // 2,097,152 output elems per batch per tensor
}

// ---------------------------------------------------------------------------
// Kernel 1: zero-fill the whole output (outs + spikes = 268 MB).
// Outputs are zero except at spikes (~0.5% of elements), written by kernel 2.
// ---------------------------------------------------------------------------
__global__ __launch_bounds__(256) void fill_zero_kernel(float4* __restrict__ out,
                                                        int n4) {
  int i = blockIdx.x * 256 + threadIdx.x;
  const int stride = gridDim.x * 256;
  const float4 z = make_float4(0.f, 0.f, 0.f, 0.f);
  for (; i < n4; i += stride) out[i] = z;
}

// ---------------------------------------------------------------------------
// Kernel 2: the sequential LIF chains. block = batch b, lane = neuron n.
// x[b][t] is lane-uniform -> scalar loads. Critical path per step is
// {v_add, v_cmp} (parallel, dep on s) -> v_cndmask  ~= 8 cycles.
//
// State trick: keep s = value AFTER adding x_t, BEFORE reset. Then
//   s_{t+1} = prev_spike ? x_{t+1} : fl(s_t + x_{t+1})
// which matches fl(acc + x) exactly, because acc = prev_spike ? 0 : s_t and
// fl(0 + x) == x for all decision-relevant purposes (zeros never exceed
// thresh >= 0, and sign-of-zero differences vanish at the first nonzero add,
// so every spike decision and every emitted value is bit-identical).
// ---------------------------------------------------------------------------
__global__ __launch_bounds__(64) void lif_sim_kernel(const float* __restrict__ x,
                                                     const float* __restrict__ thresh,
                                                     const float* __restrict__ acc0,
                                                     float* __restrict__ out) {
  const int b = blockIdx.x;
  const int n = threadIdx.x;
  const float th = thresh[n];
  const float* __restrict__ xb = x + b * kT;
  float* __restrict__ outs_b = out + (long)b * kPerB;
  float* __restrict__ spks_b = out + (long)(kB + b) * kPerB;

  // Honor acc0 (zeros in practice). s starts as the pre-add state with no
  // pending reset.
  float s = acc0[b * kN + n];
  bool prev = false;

#pragma unroll 8
  for (int t = 0; t < kT; ++t) {
    const float xt = xb[t];       // lane-uniform -> s_load broadcast
    const float u = s + xt;       // fl(s + x), on critical path
    s = prev ? xt : u;            // fl(acc + x) for both reset states
    prev = s > th;                // next step's steering, off the add chain
    if (prev) {                   // rare (~0.5%/lane); exec-masked branch
      // out index within batch b: ((t>>7) rows of S) * N*H + n*H + (t&127)
      const int idx = (t >> 7) * (kN * kH) + n * kH + (t & 127);
      outs_b[idx] = s;            // reference: out = acc at spike
      spks_b[idx] = 1.0f;         // spike flag as fp32
    }
  }
}

// ---------------------------------------------------------------------------
extern "C" void kernel_launch(void* const* d_in, const int* in_sizes, int n_in,
                              void* d_out, int out_size, void* d_ws, size_t ws_size,
                              hipStream_t stream) {
  const float* inputs = (const float*)d_in[0];    // [B, S, H] fp32
  const float* threshes = (const float*)d_in[1];  // [N] fp32
  const float* acc0 = (const float*)d_in[2];      // [B, N] fp32 (zeros)
  float* out = (float*)d_out;

  // 1) zero-fill both output tensors (268 MB); pure bandwidth.
  const int n4 = out_size / 4;  // 16,777,216 float4
  fill_zero_kernel<<<8192, 256, 0, stream>>>((float4*)out, n4);

  // 2) run the 1024 sequential chains; scattered rare spike writes land on
  //    top of the zero fill (same stream -> ordered, no race).
  lif_sim_kernel<<<kB, kN, 0, stream>>>(inputs, threshes, acc0, out);
}